// Round 7
// baseline (207.792 us; speedup 1.0000x reference)
//
#include <hip/hip_runtime.h>
#include <math.h>

// Problem constants
#define BATCH 4096
#define NFEAT 26
#define VOCAB 10000
#define EDIM 64
#define D0 1664          // NFEAT*EDIM
#define NUMB 13
#define IN_DIM 1677      // D0 + NUMB
#define H1D 1024
#define H2D 512
#define H3D 256
#define EPS 1e-5f

// ---------------------------------------------------------------------------
// Single mega-kernel, round-1-verified collapse math (absmax 0.00195):
//   z_h[row] = x . (u0*s0) + Cv,   u2 = W3^T(pw_h*s3), u1 = W2^T(u2*s2),
//   u0 = W1^T(u1*s1), Cv = u0.t0 + u1.b1' + u2.b2' + C3.
//
// ROUND-7 post-mortem of r6: the ev[2][7] "register" capture SPILLED
// (VGPR_Count=64, WRITE_SIZE 0.2->6.8MB = scratch traffic) -> still two
// memory traversals, 76.8us. FETCH=21.6MB == unique gathered-row footprint,
// i.e. the gather fetch is already minimal; kernel is LATENCY-bound at 24%
// occupancy.  Fix: abandon pre-gate overlap (worth ~12us) which cost a
// second traversal (~38us) or a spill. Fuse now gates FIRST, then ONE
// traversal computes all 5 dots (round-1 fuse_out loop verbatim). Spend the
// freed registers on occupancy: __launch_bounds__(256,8) (VGPR cap 64,
// actual ~40) + 4 rows/block x 1024 fuse blocks -> ~2x waves in flight for
// the latency-bound gather.
//
// Sync protocol (passed rounds 4 & 6, unchanged): poll RELAXED + s_sleep
// (no L2-inv storm), bounded (fail-visible, never hang); acquire re-check +
// one threadfence on trip. Writers: syncthreads -> threadfence -> release
// fetch_add.
// Phases: bid 0..15 A(u2)->B->C; 16..63 B(u1)->C; 64..111 C(u0);
//         112 Csums+C3; 113..1136 fuse(4 rows each).
//         fA(16)->B, fB(64)->C, fC(113)->fuse.
// Co-residency: 1137 blocks <= 8/CU * 256 CU = 2048 -> no spin starvation.
// ---------------------------------------------------------------------------

#define NC 113
#define NFUSE 1024
#define GRID_BLKS (NC + NFUSE)
#define TA 16
#define TB 64
#define TC 113
#define SPIN_CAP 200000

__device__ __forceinline__ void wait_flag(int* f, int target) {
    if (threadIdx.x == 0) {
        int it = 0;
        // RELAXED poll: no per-iteration cache maintenance.
        while (__hip_atomic_load(f, __ATOMIC_RELAXED, __HIP_MEMORY_SCOPE_AGENT) < target) {
            __builtin_amdgcn_s_sleep(8);
            if (++it > SPIN_CAP) break;    // fail-visible, never hang
        }
        // Acquire re-check (value used -> load not eliminable): one L2 inv.
        while (__hip_atomic_load(f, __ATOMIC_ACQUIRE, __HIP_MEMORY_SCOPE_AGENT) < target) {
            __builtin_amdgcn_s_sleep(8);
            if (++it > SPIN_CAP) break;
        }
        __threadfence();
    }
    __syncthreads();
}

__device__ __forceinline__ void post_flag(int* f) {
    __syncthreads();   // all block stores issued+drained
    if (threadIdx.x == 0) {
        __threadfence();   // write back this XCD's L2 to the coherent point
        __hip_atomic_fetch_add(f, 1, __ATOMIC_RELEASE, __HIP_MEMORY_SCOPE_AGENT);
    }
}

__global__ __launch_bounds__(256, 8) void mega(
    const float* __restrict__ numb, const int* __restrict__ cat,
    const float* __restrict__ emb, const float* __restrict__ bn0,
    const float* __restrict__ w1, const float* __restrict__ b1,
    const float* __restrict__ bn1,
    const float* __restrict__ w2, const float* __restrict__ b2,
    const float* __restrict__ bn2,
    const float* __restrict__ w3, const float* __restrict__ b3,
    const float* __restrict__ bn3,
    const float* __restrict__ cw, const float* __restrict__ cb,
    const float* __restrict__ pw, const float* __restrict__ pb,
    float* __restrict__ u2, float* __restrict__ u1, float* __restrict__ u0,
    float* __restrict__ Cv, int* __restrict__ flags,
    float* __restrict__ Csums, float* __restrict__ out) {
    const int bid = blockIdx.x, tid = threadIdx.x;
    int* fA = flags + 0;
    int* fB = flags + 1;
    int* fC = flags + 2;

    __shared__ __align__(16) float sA[1792];   // fuse: vj; collapse: a3s/part/a2s/a1s
    __shared__ float sRed[4][4];
    __shared__ int sIdx[4][NFEAT];

    if (bid < NC) {
        if (bid == 112) {
            // ---- Csums (cross/pred column sums) + C3 ----  [verified]
            float p0 = 0.f, p1 = 0.f, p2 = 0.f, p3 = 0.f;
            for (int j = tid; j < D0; j += 256) {
                p0 += cw[j]; p1 += cw[D0 + j]; p2 += cw[2 * D0 + j]; p3 += pw[j];
            }
            for (int o = 32; o > 0; o >>= 1) {
                p0 += __shfl_down(p0, o, 64); p1 += __shfl_down(p1, o, 64);
                p2 += __shfl_down(p2, o, 64); p3 += __shfl_down(p3, o, 64);
            }
            if ((tid & 63) == 0) {
                int w = tid >> 6;
                sRed[w][0] = p0; sRed[w][1] = p1; sRed[w][2] = p2; sRed[w][3] = p3;
            }
            __syncthreads();
            if (tid < 4) Csums[tid] = sRed[0][tid] + sRed[1][tid] + sRed[2][tid] + sRed[3][tid];
            __syncthreads();
            float c3;
            {   // 256 threads exactly cover H3D
                const int c = tid;
                float s3 = bn3[c] * rsqrtf(bn3[3 * H3D + c] + EPS);
                c3 = pw[D0 + c] * ((b3[c] - bn3[2 * H3D + c]) * s3 + bn3[H3D + c]);
            }
            for (int o = 32; o > 0; o >>= 1) c3 += __shfl_down(c3, o, 64);
            if ((tid & 63) == 0) sRed[tid >> 6][0] = c3;
            __syncthreads();
            if (tid == 0) atomicAdd(Cv, sRed[0][0] + sRed[1][0] + sRed[2][0] + sRed[3][0]);
            post_flag(fC);
            return;
        }

        if (bid < 16) {
            // ---- phase A: u2[32*bid .. +32) owner  [verified] ----
            {
                float s3 = bn3[tid] * rsqrtf(bn3[3 * H3D + tid] + EPS);
                sA[tid] = pw[D0 + tid] * s3;          // a3s[256]
            }
            __syncthreads();
            const int kk = tid & 31, seg = tid >> 5;
            const int k = bid * 32 + kk;
            float acc = 0.f;
#pragma unroll
            for (int i = 0; i < 32; ++i) {
                int c = seg * 32 + i;
                acc += sA[c] * w3[(size_t)c * H2D + k];   // coalesced 128B runs
            }
            sA[256 + tid] = acc;                      // part[256]
            __syncthreads();
            if (tid < 32) {
                float s = 0.f;
#pragma unroll
                for (int sg = 0; sg < 8; ++sg) s += sA[256 + sg * 32 + tid];
                const int kq = bid * 32 + tid;
                u2[kq] = s;                           // owner write
                float s2 = bn2[kq] * rsqrtf(bn2[3 * H2D + kq] + EPS);
                float beta2 = (b2[kq] - bn2[2 * H2D + kq]) * s2 + bn2[H2D + kq];
                float pc = s * beta2;
                for (int o = 16; o > 0; o >>= 1) pc += __shfl_down(pc, o, 32);
                if (tid == 0) atomicAdd(Cv, pc);      // u2.beta2 contribution
            }
            post_flag(fA);
        }

        if (bid < 64) {
            // ---- phase B: u1[n] += sum_p a2[p]*W2[p,n]  [verified] ----
            wait_flag(fA, TA);
            const int p0 = (bid >> 2) * 32;
            if (tid < 32) {
                const int p = p0 + tid;
                float s2 = bn2[p] * rsqrtf(bn2[3 * H2D + p] + EPS);
                sA[1024 + tid] = u2[p] * s2;          // a2s[32]
            }
            __syncthreads();
            const int n = (bid & 3) * 256 + tid;
            float acc = 0.f;
#pragma unroll
            for (int p = 0; p < 32; ++p)
                acc += sA[1024 + p] * w2[(size_t)(p0 + p) * H1D + n];   // coalesced
            atomicAdd(&u1[n], acc);
            float s1 = bn1[n] * rsqrtf(bn1[3 * H1D + n] + EPS);
            float beta1 = (b1[n] - bn1[2 * H1D + n]) * s1 + bn1[H1D + n];
            float pc = acc * beta1;
            for (int o = 32; o > 0; o >>= 1) pc += __shfl_down(pc, o, 64);
            if ((tid & 63) == 0) sRed[tid >> 6][0] = pc;
            __syncthreads();
            if (tid == 0) atomicAdd(Cv, sRed[0][0] + sRed[1][0] + sRed[2][0] + sRed[3][0]);
            post_flag(fB);
        }

        // ---- phase C: u0[j] += sum_n a1[n]*W1[n,j]  [verified] ----
        wait_flag(fB, TB);
        const int jc = bid % 7, n0c = (bid / 7) * 64;
        if (tid < 64) {
            const int n = n0c + tid;
            float s1 = bn1[n] * rsqrtf(bn1[3 * H1D + n] + EPS);
            sA[tid] = u1[n] * s1;                     // a1s[64]
        }
        __syncthreads();
        const int j = jc * 256 + tid;
        float pc = 0.f;
        if (j < IN_DIM) {
            float acc = 0.f;
#pragma unroll 8
            for (int n = 0; n < 64; ++n)
                acc += sA[n] * w1[(size_t)(n0c + n) * IN_DIM + j];   // coalesced
            atomicAdd(&u0[j], acc);
            float s0 = bn0[j] * rsqrtf(bn0[3 * IN_DIM + j] + EPS);
            float t0 = bn0[IN_DIM + j] - bn0[2 * IN_DIM + j] * s0;
            pc = acc * t0;
        }
        for (int o = 32; o > 0; o >>= 1) pc += __shfl_down(pc, o, 64);
        if ((tid & 63) == 0) sRed[tid >> 6][0] = pc;
        __syncthreads();
        if (tid == 0) atomicAdd(Cv, sRed[0][0] + sRed[1][0] + sRed[2][0] + sRed[3][0]);
        post_flag(fC);
        return;
    }

    // ---- fuse: gate FIRST, then ONE traversal with all 5 dots ----
    // 4 rows/block, 1 row/wave. Round-1 fuse_out inner loop verbatim.
    const int b0 = (bid - NC) * 4;
    if (tid < 4 * NFEAT)
        sIdx[tid / NFEAT][tid % NFEAT] = cat[(b0 + tid / NFEAT) * NFEAT + tid % NFEAT];
    // wait_flag ends with __syncthreads -> also publishes sIdx block-wide.
    wait_flag(fC, TC);

    for (int j = tid; j < IN_DIM; j += 256) {
        float s0 = bn0[j] * rsqrtf(bn0[3 * IN_DIM + j] + EPS);
        sA[j] = u0[j] * s0;                           // vj
    }
    __syncthreads();

    const int wave = tid >> 6, lane = tid & 63;
    const float4* cw0 = (const float4*)cw;
    const float4* cw1 = (const float4*)(cw + D0);
    const float4* cw2 = (const float4*)(cw + 2 * D0);
    const float4* pw4 = (const float4*)pw;

    const int r = wave, b = b0 + r;
    float d0 = 0.f, d1 = 0.f, d2 = 0.f, dp = 0.f, dv = 0.f;
    for (int j = lane; j < D0 / 4; j += 64) {
        int f = j >> 4, d4 = j & 15;
        float4 v = *(const float4*)&emb[((size_t)f * VOCAB + sIdx[r][f]) * EDIM + d4 * 4];
        float4 c0 = cw0[j], c1 = cw1[j], c2 = cw2[j], p4 = pw4[j];
        float4 vv = *(const float4*)&sA[j * 4];
        d0 += v.x * c0.x + v.y * c0.y + v.z * c0.z + v.w * c0.w;
        d1 += v.x * c1.x + v.y * c1.y + v.z * c1.z + v.w * c1.w;
        d2 += v.x * c2.x + v.y * c2.y + v.z * c2.z + v.w * c2.w;
        dp += v.x * p4.x + v.y * p4.y + v.z * p4.z + v.w * p4.w;
        dv += v.x * vv.x + v.y * vv.y + v.z * vv.z + v.w * vv.w;
    }
    for (int o = 32; o > 0; o >>= 1) {
        d0 += __shfl_down(d0, o, 64); d1 += __shfl_down(d1, o, 64);
        d2 += __shfl_down(d2, o, 64); dp += __shfl_down(dp, o, 64);
        dv += __shfl_down(dv, o, 64);
    }
    if (lane == 0) {
        float dn = 0.f;
#pragma unroll
        for (int t = 0; t < NUMB; ++t) dn += numb[b * NUMB + t] * sA[D0 + t];
        float P = 1.f, Q = 0.f;
        float dd[3] = {d0, d1, d2};
#pragma unroll
        for (int i = 0; i < 3; i++) {
            float s = 1.f + P * dd[i] + Q * Csums[i];
            P = s * P;
            Q = s * Q + cb[i];
        }
        float z = P * dp + Q * Csums[3] + dv + dn + Cv[0] + pb[0];
        out[b] = 1.f / (1.f + expf(-z));
    }
}

// ---------------------------------------------------------------------------
extern "C" void kernel_launch(void* const* d_in, const int* in_sizes, int n_in,
                              void* d_out, int out_size, void* d_ws, size_t ws_size,
                              hipStream_t stream) {
    const float* numb = (const float*)d_in[0];
    const int* cat = (const int*)d_in[1];
    const float* emb = (const float*)d_in[2];
    const float* bn0 = (const float*)d_in[3];
    const float* w1 = (const float*)d_in[4];
    const float* b1 = (const float*)d_in[5];
    const float* bn1 = (const float*)d_in[6];
    const float* w2 = (const float*)d_in[7];
    const float* b2 = (const float*)d_in[8];
    const float* bn2 = (const float*)d_in[9];
    const float* w3 = (const float*)d_in[10];
    const float* b3 = (const float*)d_in[11];
    const float* bn3 = (const float*)d_in[12];
    const float* cw = (const float*)d_in[13];
    const float* cb = (const float*)d_in[14];
    const float* pw = (const float*)d_in[15];
    const float* pb = (const float*)d_in[16];
    float* out = (float*)d_out;

    char* ws = (char*)d_ws;
    // workspace layout (bytes):
    float* u2    = (float*)(ws + 0);      // 512 f, owner-written (no zero)
    // ---- zeroed region starts at +2048 ----
    float* u1    = (float*)(ws + 2048);   // 1024 f (atomic accumulate)
    float* u0    = (float*)(ws + 6144);   // 1792 f (atomic accumulate; 1677 used)
    float* Cv    = (float*)(ws + 13312);  // 1 f + pad (atomic accumulate)
    int*   flags = (int*)(ws + 13328);    // fA, fB, fC
    // ---- zeroed region ends at +13344 (11296 bytes) ----
    float* Csums = (float*)(ws + 13344);  // 4 f, owner-written

    // One fill node zeroes accumulators + flags (poison-proof), then ONE
    // kernel dispatch does everything.
    hipMemsetAsync(ws + 2048, 0, 11296, stream);
    mega<<<GRID_BLKS, 256, 0, stream>>>(
        numb, cat, emb, bn0, w1, b1, bn1, w2, b2, bn2, w3, b3, bn3,
        cw, cb, pw, pb, u2, u1, u0, Cv, flags, Csums, out);
}

// Round 8
// 157.324 us; speedup vs baseline: 1.3208x; 1.3208x over previous
//
#include <hip/hip_runtime.h>
#include <math.h>

// Problem constants
#define BATCH 4096
#define NFEAT 26
#define VOCAB 10000
#define EDIM 64
#define D0 1664          // NFEAT*EDIM
#define NUMB 13
#define IN_DIM 1677      // D0 + NUMB
#define H1D 1024
#define H2D 512
#define H3D 256
#define EPS 1e-5f

// ---------------------------------------------------------------------------
// Affine-collapse math (verified rounds 1/2/4/6/7, absmax 0.00195):
//   z_h[row] = x . (u0*s0) + Cv,   u2 = W3^T(pw_h*s3), u1 = W2^T(u2*s2),
//   u0 = W1^T(u1*s1), Cv = u0.t0 + u1.b1' + u2.b2' + C3.
//
// ROUND-8 STRUCTURE: 2 dispatches + memset.
// Post-mortem of the mega experiment (r2-r7): the single-dispatch design
// never beat r1's 150.0us. r7 isolated why: (a) launch_bounds(256,8) cut
// VGPR to 32 -> the 5-stream dot loop lost its load pipelining (105us @
// 186GB/s); (b) 1100 fuse blocks hot-polling one L3 line during the whole
// collapse window. The dispatch boundary is cheaper than a grid-scale flag
// gate. Flags stay ONLY where proven cheap: among the 113 collapse blocks
// (<=96 staggered pollers; protocol passed r4/r6/r7).
//   dispatch 1: collapse  (113 blocks; A(0-15)->B(0-63)->C(0-111), 112=Csums)
//   dispatch 2: fuse_out  (512 blocks x 8 rows; ONE traversal, 5 dots,
//               2 rows interleaved per wave: 2 independent emb streams,
//               weight streams amortized over both rows; no VGPR clamp)
// ---------------------------------------------------------------------------

#define TA 16
#define TB 64
#define SPIN_CAP 200000

__device__ __forceinline__ void wait_flag(int* f, int target) {
    if (threadIdx.x == 0) {
        int it = 0;
        // RELAXED poll: no per-iteration cache maintenance (r2 lesson).
        while (__hip_atomic_load(f, __ATOMIC_RELAXED, __HIP_MEMORY_SCOPE_AGENT) < target) {
            __builtin_amdgcn_s_sleep(8);
            if (++it > SPIN_CAP) break;    // fail-visible, never hang
        }
        // Acquire re-check (value used -> not eliminable): one L2 inv.
        while (__hip_atomic_load(f, __ATOMIC_ACQUIRE, __HIP_MEMORY_SCOPE_AGENT) < target) {
            __builtin_amdgcn_s_sleep(8);
            if (++it > SPIN_CAP) break;
        }
        __threadfence();
    }
    __syncthreads();
}

__device__ __forceinline__ void post_flag(int* f) {
    __syncthreads();   // all block stores issued+drained
    if (threadIdx.x == 0) {
        __threadfence();   // write back this XCD's L2 to the coherent point
        __hip_atomic_fetch_add(f, 1, __ATOMIC_RELEASE, __HIP_MEMORY_SCOPE_AGENT);
    }
}

// ---------------------------------------------------------------------------
// collapse: one dispatch, 113 blocks.
//   bid 0..15  : phase A (u2 chunk owner)          -> post fA
//   bid 0..63  : phase B (u1 atomic accumulate)    -> wait fA, post fB
//   bid 0..111 : phase C (u0 atomic accumulate)    -> wait fB
//   bid 112    : Csums + C3 (independent)
// All phase bodies verbatim from the verified kernels.
// ---------------------------------------------------------------------------
__global__ __launch_bounds__(256) void collapse(
    const float* __restrict__ w1, const float* __restrict__ b1,
    const float* __restrict__ bn1,
    const float* __restrict__ w2, const float* __restrict__ b2,
    const float* __restrict__ bn2,
    const float* __restrict__ w3, const float* __restrict__ b3,
    const float* __restrict__ bn3,
    const float* __restrict__ bn0,
    const float* __restrict__ cw, const float* __restrict__ pw,
    float* __restrict__ u2, float* __restrict__ u1, float* __restrict__ u0,
    float* __restrict__ Cv, int* __restrict__ flags,
    float* __restrict__ Csums) {
    const int bid = blockIdx.x, tid = threadIdx.x;
    int* fA = flags + 0;
    int* fB = flags + 1;

    __shared__ __align__(16) float sA[1280];
    __shared__ float sRed[4][4];

    if (bid == 112) {
        // ---- Csums (cross/pred column sums) + C3 -> Cv ----  [verified]
        float p0 = 0.f, p1 = 0.f, p2 = 0.f, p3 = 0.f;
        for (int j = tid; j < D0; j += 256) {
            p0 += cw[j]; p1 += cw[D0 + j]; p2 += cw[2 * D0 + j]; p3 += pw[j];
        }
        for (int o = 32; o > 0; o >>= 1) {
            p0 += __shfl_down(p0, o, 64); p1 += __shfl_down(p1, o, 64);
            p2 += __shfl_down(p2, o, 64); p3 += __shfl_down(p3, o, 64);
        }
        if ((tid & 63) == 0) {
            int w = tid >> 6;
            sRed[w][0] = p0; sRed[w][1] = p1; sRed[w][2] = p2; sRed[w][3] = p3;
        }
        __syncthreads();
        if (tid < 4) Csums[tid] = sRed[0][tid] + sRed[1][tid] + sRed[2][tid] + sRed[3][tid];
        __syncthreads();
        float c3;
        {   // 256 threads exactly cover H3D
            const int c = tid;
            float s3 = bn3[c] * rsqrtf(bn3[3 * H3D + c] + EPS);
            c3 = pw[D0 + c] * ((b3[c] - bn3[2 * H3D + c]) * s3 + bn3[H3D + c]);
        }
        for (int o = 32; o > 0; o >>= 1) c3 += __shfl_down(c3, o, 64);
        if ((tid & 63) == 0) sRed[tid >> 6][0] = c3;
        __syncthreads();
        if (tid == 0) atomicAdd(Cv, sRed[0][0] + sRed[1][0] + sRed[2][0] + sRed[3][0]);
        return;
    }

    if (bid < 16) {
        // ---- phase A: u2[32*bid .. +32) owner  [verified] ----
        {
            float s3 = bn3[tid] * rsqrtf(bn3[3 * H3D + tid] + EPS);
            sA[tid] = pw[D0 + tid] * s3;          // a3s[256]
        }
        __syncthreads();
        const int kk = tid & 31, seg = tid >> 5;
        const int k = bid * 32 + kk;
        float acc = 0.f;
#pragma unroll
        for (int i = 0; i < 32; ++i) {
            int c = seg * 32 + i;
            acc += sA[c] * w3[(size_t)c * H2D + k];   // coalesced 128B runs
        }
        sA[256 + tid] = acc;                      // part[256]
        __syncthreads();
        if (tid < 32) {
            float s = 0.f;
#pragma unroll
            for (int sg = 0; sg < 8; ++sg) s += sA[256 + sg * 32 + tid];
            const int kq = bid * 32 + tid;
            u2[kq] = s;                           // owner write
            float s2 = bn2[kq] * rsqrtf(bn2[3 * H2D + kq] + EPS);
            float beta2 = (b2[kq] - bn2[2 * H2D + kq]) * s2 + bn2[H2D + kq];
            float pc = s * beta2;
            for (int o = 16; o > 0; o >>= 1) pc += __shfl_down(pc, o, 32);
            if (tid == 0) atomicAdd(Cv, pc);      // u2.beta2 contribution
        }
        post_flag(fA);
    }

    if (bid < 64) {
        // ---- phase B: u1[n] += sum_p a2[p]*W2[p,n]  [verified] ----
        wait_flag(fA, TA);
        const int p0 = (bid >> 2) * 32;
        if (tid < 32) {
            const int p = p0 + tid;
            float s2 = bn2[p] * rsqrtf(bn2[3 * H2D + p] + EPS);
            sA[1024 + tid] = u2[p] * s2;          // a2s[32]
        }
        __syncthreads();
        const int n = (bid & 3) * 256 + tid;
        float acc = 0.f;
#pragma unroll
        for (int p = 0; p < 32; ++p)
            acc += sA[1024 + p] * w2[(size_t)(p0 + p) * H1D + n];   // coalesced
        atomicAdd(&u1[n], acc);
        float s1 = bn1[n] * rsqrtf(bn1[3 * H1D + n] + EPS);
        float beta1 = (b1[n] - bn1[2 * H1D + n]) * s1 + bn1[H1D + n];
        float pc = acc * beta1;
        for (int o = 32; o > 0; o >>= 1) pc += __shfl_down(pc, o, 64);
        if ((tid & 63) == 0) sRed[tid >> 6][0] = pc;
        __syncthreads();
        if (tid == 0) atomicAdd(Cv, sRed[0][0] + sRed[1][0] + sRed[2][0] + sRed[3][0]);
        post_flag(fB);
    }

    // ---- phase C: u0[j] += sum_n a1[n]*W1[n,j]  [verified] ----
    wait_flag(fB, TB);
    const int jc = bid % 7, n0c = (bid / 7) * 64;
    if (tid < 64) {
        const int n = n0c + tid;
        float s1 = bn1[n] * rsqrtf(bn1[3 * H1D + n] + EPS);
        sA[tid] = u1[n] * s1;                     // a1s[64]
    }
    __syncthreads();
    const int j = jc * 256 + tid;
    float pc = 0.f;
    if (j < IN_DIM) {
        float acc = 0.f;
#pragma unroll 8
        for (int n = 0; n < 64; ++n)
            acc += sA[n] * w1[(size_t)(n0c + n) * IN_DIM + j];   // coalesced
        atomicAdd(&u0[j], acc);
        float s0 = bn0[j] * rsqrtf(bn0[3 * IN_DIM + j] + EPS);
        float t0 = bn0[IN_DIM + j] - bn0[2 * IN_DIM + j] * s0;
        pc = acc * t0;
    }
    for (int o = 32; o > 0; o >>= 1) pc += __shfl_down(pc, o, 64);
    if ((tid & 63) == 0) sRed[tid >> 6][0] = pc;
    __syncthreads();
    if (tid == 0) atomicAdd(Cv, sRed[0][0] + sRed[1][0] + sRed[2][0] + sRed[3][0]);
    // kernel end = device-wide barrier + L2 writeback before fuse_out
}

// ---------------------------------------------------------------------------
// fuse_out: 512 blocks x 8 rows (2 rows per wave, INTERLEAVED in one j-loop:
// 2 independent emb streams per wave, weight streams amortized over both
// rows). Per-row accumulation order identical to round 1 (verified).
// ---------------------------------------------------------------------------
__global__ __launch_bounds__(256) void fuse_out(
    const float* __restrict__ numb, const int* __restrict__ cat,
    const float* __restrict__ emb, const float* __restrict__ bn0,
    const float* __restrict__ cw, const float* __restrict__ cb,
    const float* __restrict__ pw, const float* __restrict__ pb,
    const float* __restrict__ u0, const float* __restrict__ Cv,
    const float* __restrict__ Csums, float* __restrict__ out) {
    __shared__ __align__(16) float vj[IN_DIM + 3];
    __shared__ int idx[8][NFEAT];
    const int bid = blockIdx.x, tid = threadIdx.x;
    const int rowbase = bid * 8;

    for (int j = tid; j < IN_DIM; j += 256) {
        float s0 = bn0[j] * rsqrtf(bn0[3 * IN_DIM + j] + EPS);
        vj[j] = u0[j] * s0;
    }
    if (tid < 8 * NFEAT)
        idx[tid / NFEAT][tid % NFEAT] = cat[(rowbase + tid / NFEAT) * NFEAT + tid % NFEAT];
    __syncthreads();

    const int wave = tid >> 6, lane = tid & 63;
    const int rA = wave * 2, rB = wave * 2 + 1;
    const float4* cw0 = (const float4*)cw;
    const float4* cw1 = (const float4*)(cw + D0);
    const float4* cw2 = (const float4*)(cw + 2 * D0);
    const float4* pw4 = (const float4*)pw;

    float a0 = 0.f, a1 = 0.f, a2 = 0.f, ap = 0.f, av = 0.f;   // row rA
    float e0 = 0.f, e1 = 0.f, e2 = 0.f, ep = 0.f, ev = 0.f;   // row rB
    for (int j = lane; j < D0 / 4; j += 64) {
        const int f = j >> 4, d4 = j & 15;
        const float4 va = *(const float4*)&emb[((size_t)f * VOCAB + idx[rA][f]) * EDIM + d4 * 4];
        const float4 vb = *(const float4*)&emb[((size_t)f * VOCAB + idx[rB][f]) * EDIM + d4 * 4];
        const float4 c0 = cw0[j], c1 = cw1[j], c2 = cw2[j], p4 = pw4[j];
        const float4 vv = *(const float4*)&vj[j * 4];
        a0 += va.x * c0.x + va.y * c0.y + va.z * c0.z + va.w * c0.w;
        a1 += va.x * c1.x + va.y * c1.y + va.z * c1.z + va.w * c1.w;
        a2 += va.x * c2.x + va.y * c2.y + va.z * c2.z + va.w * c2.w;
        ap += va.x * p4.x + va.y * p4.y + va.z * p4.z + va.w * p4.w;
        av += va.x * vv.x + va.y * vv.y + va.z * vv.z + va.w * vv.w;
        e0 += vb.x * c0.x + vb.y * c0.y + vb.z * c0.z + vb.w * c0.w;
        e1 += vb.x * c1.x + vb.y * c1.y + vb.z * c1.z + vb.w * c1.w;
        e2 += vb.x * c2.x + vb.y * c2.y + vb.z * c2.z + vb.w * c2.w;
        ep += vb.x * p4.x + vb.y * p4.y + vb.z * p4.z + vb.w * p4.w;
        ev += vb.x * vv.x + vb.y * vv.y + vb.z * vv.z + vb.w * vv.w;
    }
    for (int o = 32; o > 0; o >>= 1) {
        a0 += __shfl_down(a0, o, 64); a1 += __shfl_down(a1, o, 64);
        a2 += __shfl_down(a2, o, 64); ap += __shfl_down(ap, o, 64);
        av += __shfl_down(av, o, 64);
        e0 += __shfl_down(e0, o, 64); e1 += __shfl_down(e1, o, 64);
        e2 += __shfl_down(e2, o, 64); ep += __shfl_down(ep, o, 64);
        ev += __shfl_down(ev, o, 64);
    }
    if (lane == 0) {
        {   // row rA
            const int b = rowbase + rA;
            float dn = 0.f;
#pragma unroll
            for (int t = 0; t < NUMB; ++t) dn += numb[b * NUMB + t] * vj[D0 + t];
            float P = 1.f, Q = 0.f;
            float dd[3] = {a0, a1, a2};
#pragma unroll
            for (int i = 0; i < 3; i++) {
                float s = 1.f + P * dd[i] + Q * Csums[i];
                P = s * P;
                Q = s * Q + cb[i];
            }
            float z = P * ap + Q * Csums[3] + av + dn + Cv[0] + pb[0];
            out[b] = 1.f / (1.f + expf(-z));
        }
        {   // row rB
            const int b = rowbase + rB;
            float dn = 0.f;
#pragma unroll
            for (int t = 0; t < NUMB; ++t) dn += numb[b * NUMB + t] * vj[D0 + t];
            float P = 1.f, Q = 0.f;
            float dd[3] = {e0, e1, e2};
#pragma unroll
            for (int i = 0; i < 3; i++) {
                float s = 1.f + P * dd[i] + Q * Csums[i];
                P = s * P;
                Q = s * Q + cb[i];
            }
            float z = P * ep + Q * Csums[3] + ev + dn + Cv[0] + pb[0];
            out[b] = 1.f / (1.f + expf(-z));
        }
    }
}

// ---------------------------------------------------------------------------
extern "C" void kernel_launch(void* const* d_in, const int* in_sizes, int n_in,
                              void* d_out, int out_size, void* d_ws, size_t ws_size,
                              hipStream_t stream) {
    const float* numb = (const float*)d_in[0];
    const int* cat = (const int*)d_in[1];
    const float* emb = (const float*)d_in[2];
    const float* bn0 = (const float*)d_in[3];
    const float* w1 = (const float*)d_in[4];
    const float* b1 = (const float*)d_in[5];
    const float* bn1 = (const float*)d_in[6];
    const float* w2 = (const float*)d_in[7];
    const float* b2 = (const float*)d_in[8];
    const float* bn2 = (const float*)d_in[9];
    const float* w3 = (const float*)d_in[10];
    const float* b3 = (const float*)d_in[11];
    const float* bn3 = (const float*)d_in[12];
    const float* cw = (const float*)d_in[13];
    const float* cb = (const float*)d_in[14];
    const float* pw = (const float*)d_in[15];
    const float* pb = (const float*)d_in[16];
    float* out = (float*)d_out;

    char* ws = (char*)d_ws;
    // workspace layout (bytes):
    float* u2    = (float*)(ws + 0);      // 512 f, owner-written (no zero)
    // ---- zeroed region starts at +2048 ----
    float* u1    = (float*)(ws + 2048);   // 1024 f (atomic accumulate)
    float* u0    = (float*)(ws + 6144);   // 1792 f (atomic accumulate; 1677 used)
    float* Cv    = (float*)(ws + 13312);  // 1 f + pad (atomic accumulate)
    int*   flags = (int*)(ws + 13328);    // fA, fB
    // ---- zeroed region ends at +13344 (11296 bytes) ----
    float* Csums = (float*)(ws + 13344);  // 4 f, owner-written

    // One fill node zeroes accumulators + flags (poison-proof).
    hipMemsetAsync(ws + 2048, 0, 11296, stream);
    // Collapse chain: 1 dispatch, internal flags (113 blocks, <=96 pollers).
    collapse<<<113, 256, 0, stream>>>(
        w1, b1, bn1, w2, b2, bn2, w3, b3, bn3, bn0, cw, pw,
        u2, u1, u0, Cv, flags, Csums);
    // Fuse: dispatch boundary is the gate (no grid-scale spin).
    fuse_out<<<512, 256, 0, stream>>>(
        numb, cat, emb, bn0, cw, cb, pw, pb, u0, Cv, Csums, out);
}